// Round 3
// baseline (167.757 us; speedup 1.0000x reference)
//
#include <hip/hip_runtime.h>
#include <math.h>

// WL1 loss over [B=16, C=3, H=512, W=512] fp32.
//   r = sum_c|hr-sr|/255 ; e = sum_c|hr-ema|/255
//   patch_w[b] = (unbiased var of r over sample)^0.2
//   pixel_w = unbiased 3x3 local var of r (reflect pad)
//   loss = mean(|w*sr - w*hr|) = (1/N) sum patch_w * pixel_w * mask * 255*r
//
// R4 == R3 resubmit (previous round failed on container acquire, not kernel).
// R3: MLP fix. R1 geometry (16x256 tile, 1024 blocks, wave-uniform rs=tid>>6)
// but ALL global loads moved before the barrier: output-row ownership remapped
// to o = row-1 so each thread's e-row reuses its own Stage-A hr registers
// (ema loaded alongside, slot it&3 -> constant index). hr Stage-B re-read
// eliminated. __launch_bounds__(256,4) -> 128 VGPR budget for deep load
// pipelining (R2's (256,8) cap collapsed VGPRs to 28 and serialized loads).

#define BB 16
#define HH 512
#define WW 512
#define HW (HH * WW)
#define CHW (3 * HW)
#define TILES_PER_BATCH 64  // 32 (h) x 2 (w)
#define NBLOCKS (BB * TILES_PER_BATCH)
#define LDS_STRIDE 264      // col 3 = left halo, 4..259 = centers, 260 = right halo

__device__ __forceinline__ int reflect_h(int gh) {
  gh = gh < 0 ? -gh : gh;
  return gh >= HH ? 2 * HH - 2 - gh : gh;
}

__global__ __launch_bounds__(256, 4) void wl1_main(
    const float* __restrict__ sr, const float* __restrict__ srema,
    const float* __restrict__ hr,
    float* __restrict__ p_sum, float* __restrict__ p_sum2,
    float* __restrict__ p_loss) {
  __shared__ float rt[18][LDS_STRIDE];
  const int bid = blockIdx.x;
  const int b = bid >> 6;
  const int t = bid & 63;
  const int h0 = (t >> 1) << 4;  // 0,16,...,496
  const int w0 = (t & 1) << 8;   // 0 or 256
  const int tid = threadIdx.x;
  const int c4 = tid & 63;       // float4 column group (0..63)
  const int rs = tid >> 6;       // row-sub (0..3) == wave id -> uniform branches
  const float* __restrict__ srb = sr + (size_t)b * CHW;
  const float* __restrict__ hrb = hr + (size_t)b * CHW;
  const float* __restrict__ eb = srema + (size_t)b * CHW;

  // Stage A2 first: left/right halo columns (36 scalar items) -> loads in flight early
  if (tid < 36) {
    int row = tid >> 1, side = tid & 1;
    int gh = reflect_h(h0 - 1 + row);
    int gw = side ? w0 + 256 : w0 - 1;
    if (gw < 0) gw = 1;
    if (gw > 511) gw = 1022 - gw;
    int base = gh * WW + gw;
    float v = (fabsf(hrb[base] - srb[base]) +
               fabsf(hrb[base + HW] - srb[base + HW]) +
               fabsf(hrb[base + 2 * HW] - srb[base + 2 * HW])) /
              255.0f;
    rt[row][side ? 260 : 3] = v;
  }

  // Stage A: 18 halo rows of r -> LDS (rows 4*it+rs); e for interior rows
  // (1..16) computed here reusing the hr registers, stored at slot it&3.
  // All conditions are wave-uniform (rs uniform per wave).
  float e_r[4][4];
#pragma unroll
  for (int it = 0; it < 5; ++it) {
    const int row = 4 * it + rs;
    if (row < 18) {
      const int gh = reflect_h(h0 - 1 + row);
      const float* hb = hrb + gh * WW + w0 + 4 * c4;
      const float* sb = srb + gh * WW + w0 + 4 * c4;
      float4 ha = *(const float4*)(hb);
      float4 hbv = *(const float4*)(hb + HW);
      float4 hc = *(const float4*)(hb + 2 * HW);
      float4 sa = *(const float4*)(sb);
      float4 sbv = *(const float4*)(sb + HW);
      float4 sc = *(const float4*)(sb + 2 * HW);
      const bool do_e = (row >= 1) && (row <= 16);
      float4 ea, eb2, ec;
      if (do_e) {
        // interior: gh == h0 + row - 1, no reflect
        const float* ep = eb + gh * WW + w0 + 4 * c4;
        ea = *(const float4*)(ep);
        eb2 = *(const float4*)(ep + HW);
        ec = *(const float4*)(ep + 2 * HW);
      }
      float4 r4;
      r4.x = (fabsf(ha.x - sa.x) + fabsf(hbv.x - sbv.x) + fabsf(hc.x - sc.x)) / 255.0f;
      r4.y = (fabsf(ha.y - sa.y) + fabsf(hbv.y - sbv.y) + fabsf(hc.y - sc.y)) / 255.0f;
      r4.z = (fabsf(ha.z - sa.z) + fabsf(hbv.z - sbv.z) + fabsf(hc.z - sc.z)) / 255.0f;
      r4.w = (fabsf(ha.w - sa.w) + fabsf(hbv.w - sbv.w) + fabsf(hc.w - sc.w)) / 255.0f;
      *(float4*)&rt[row][4 + 4 * c4] = r4;
      if (do_e) {
        // slot it&3: rs==0 writes its 1..4 -> slots 1,2,3,0 ; rs>=1 writes 0..3
        e_r[it & 3][0] = (fabsf(ha.x - ea.x) + fabsf(hbv.x - eb2.x) + fabsf(hc.x - ec.x)) / 255.0f;
        e_r[it & 3][1] = (fabsf(ha.y - ea.y) + fabsf(hbv.y - eb2.y) + fabsf(hc.y - ec.y)) / 255.0f;
        e_r[it & 3][2] = (fabsf(ha.z - ea.z) + fabsf(hbv.z - eb2.z) + fabsf(hc.z - ec.z)) / 255.0f;
        e_r[it & 3][3] = (fabsf(ha.w - ea.w) + fabsf(hbv.w - eb2.w) + fabsf(hc.w - ec.w)) / 255.0f;
      }
    }
  }
  __syncthreads();

  // Stage B: pure LDS+VALU. Thread owns output rows o = 4*it+rs-1 for the
  // valid iterations (same rows whose e it computed). 4 cols per row.
  float v1 = 0.f, v2 = 0.f, v3 = 0.f;
#pragma unroll
  for (int it = 0; it < 5; ++it) {
    const int row = 4 * it + rs;
    if (row >= 1 && row <= 16) {
      const int o = row - 1;  // output row within tile; LDS center row = row
      float cs[6] = {0, 0, 0, 0, 0, 0}, cq[6] = {0, 0, 0, 0, 0, 0};
      float center[4];
#pragma unroll
      for (int dr = 0; dr < 3; ++dr) {
        const float* lp = &rt[o + dr][4 * c4];
        float4 a = *(const float4*)(lp);
        float4 bq = *(const float4*)(lp + 4);
        float4 cq4 = *(const float4*)(lp + 8);
        float f3 = a.w, f4 = bq.x, f5 = bq.y, f6 = bq.z, f7 = bq.w, f8 = cq4.x;
        cs[0] += f3; cq[0] += f3 * f3;
        cs[1] += f4; cq[1] += f4 * f4;
        cs[2] += f5; cq[2] += f5 * f5;
        cs[3] += f6; cq[3] += f6 * f6;
        cs[4] += f7; cq[4] += f7 * f7;
        cs[5] += f8; cq[5] += f8 * f8;
        if (dr == 1) { center[0] = f4; center[1] = f5; center[2] = f6; center[3] = f7; }
      }
#pragma unroll
      for (int cc = 0; cc < 4; ++cc) {
        float s = cs[cc] + cs[cc + 1] + cs[cc + 2];
        float q = cq[cc] + cq[cc + 1] + cq[cc + 2];
        float pvar = (q - s * s / 9.0f) / 8.0f;
        float rc = center[cc];
        v1 += rc;
        v2 += rc * rc;
        if (rc >= e_r[it & 3][cc]) v3 += pvar * (255.0f * rc);
      }
    }
  }

  // block reduce (4 waves)
#pragma unroll
  for (int off = 32; off > 0; off >>= 1) {
    v1 += __shfl_down(v1, off, 64);
    v2 += __shfl_down(v2, off, 64);
    v3 += __shfl_down(v3, off, 64);
  }
  __shared__ float red[3][4];
  if (c4 == 0) {
    red[0][rs] = v1;
    red[1][rs] = v2;
    red[2][rs] = v3;
  }
  __syncthreads();
  if (tid == 0) {
    p_sum[bid] = red[0][0] + red[0][1] + red[0][2] + red[0][3];
    p_sum2[bid] = red[1][0] + red[1][1] + red[1][2] + red[1][3];
    p_loss[bid] = red[2][0] + red[2][1] + red[2][2] + red[2][3];
  }
}

// Single fused reduction: wave w handles batch w (64 partials each).
__global__ __launch_bounds__(1024) void wl1_reduce(
    const float* __restrict__ p_sum, const float* __restrict__ p_sum2,
    const float* __restrict__ p_loss, float* __restrict__ out) {
  const int tid = threadIdx.x;
  const int b = tid >> 6, k = tid & 63;
  const int i = b * TILES_PER_BATCH + k;
  double s = (double)p_sum[i], s2 = (double)p_sum2[i], sl = (double)p_loss[i];
#pragma unroll
  for (int off = 32; off > 0; off >>= 1) {
    s += __shfl_down(s, off, 64);
    s2 += __shfl_down(s2, off, 64);
    sl += __shfl_down(sl, off, 64);
  }
  __shared__ double acc[BB];
  if (k == 0) {
    const double n = (double)HW;
    double var = (s2 - s * s / n) / (n - 1.0);
    acc[b] = pow(var, 0.2) * sl;
  }
  __syncthreads();
  if (tid == 0) {
    double tot = 0.0;
#pragma unroll
    for (int j = 0; j < BB; ++j) tot += acc[j];
    out[0] = (float)(tot / (double)((size_t)BB * CHW));
  }
}

extern "C" void kernel_launch(void* const* d_in, const int* in_sizes, int n_in,
                              void* d_out, int out_size, void* d_ws,
                              size_t ws_size, hipStream_t stream) {
  const float* sr = (const float*)d_in[0];
  const float* srema = (const float*)d_in[1];
  const float* hr = (const float*)d_in[2];
  float* out = (float*)d_out;

  float* p_sum = (float*)d_ws;
  float* p_sum2 = p_sum + NBLOCKS;
  float* p_loss = p_sum2 + NBLOCKS;

  wl1_main<<<NBLOCKS, 256, 0, stream>>>(sr, srema, hr, p_sum, p_sum2, p_loss);
  wl1_reduce<<<1, 1024, 0, stream>>>(p_sum, p_sum2, p_loss, out);
}